// Round 3
// baseline (162.906 us; speedup 1.0000x reference)
//
#include <hip/hip_runtime.h>

// ---- problem constants (fixed by reference setup_inputs) ----
constexpr int B_  = 32;
constexpr int Na  = 512;
constexpr int Nv  = 256;
constexpr int D   = 384;

constexpr int NK  = D / 32;    // 12 k-chunks of 32

// fp8 operand regions: one 32-row group x 384 k = 12 chunks x 1 KB = 12 KB.
// Unit (group, kc) internal layout: byte = h2*512 + r*16 + j, holding
// value[row r][k = kc*32 + h2*16 + j]  (r = lane&31, k-half h2 = lane>>5).
// The (lane,byte)->k permutation is IDENTICAL for the MFMA A-slot and B-slot,
// so the contraction is exact for either operand role -> operands swappable.
constexpr int AGROUPS = B_ * 16;   // 512 groups (bi*16+rg), rows linear
constexpr int BGROUPS = B_ * 8;    // 256 groups (bj*8+cg), rows linear
constexpr size_t GROUP_BYTES = 12 * 1024;

typedef long  long2v   __attribute__((ext_vector_type(2)));
typedef int   int4v    __attribute__((ext_vector_type(4)));
typedef float floatx16 __attribute__((ext_vector_type(16)));

// ---- K1: zero output + fp32 -> fp8(e4m3 OCP) conversion, BOTH sides coalesced ----
__global__ void convert_fp8_kernel(const float* __restrict__ a, const float* __restrict__ v,
                                   unsigned char* __restrict__ a8,
                                   unsigned char* __restrict__ b8,
                                   float* __restrict__ out) {
    int gid = blockIdx.x * blockDim.x + threadIdx.x;
    if (gid < B_ * B_) out[gid] = 0.0f;    // d_out is poisoned before every launch

    const float* src;
    unsigned char* dst;
    int blk = blockIdx.x;
    if (blk < AGROUPS) {                       // A rows are linear: group*32 + r
        src = a + (size_t)blk * 32 * D;
        dst = a8 + (size_t)blk * GROUP_BYTES;
    } else {
        int b2 = blk - AGROUPS;
        src = v + (size_t)b2 * 32 * D;
        dst = b8 + (size_t)b2 * GROUP_BYTES;
    }
    const int t = threadIdx.x;
    const int r = t >> 3, q = t & 7;

    #pragma unroll
    for (int p = 0; p < 3; ++p) {
        int k0 = p * 128 + q * 16;
        const float4* s4 = (const float4*)(src + (size_t)r * D + k0);
        float4 f0 = s4[0], f1 = s4[1], f2 = s4[2], f3 = s4[3];
        int w0 = 0, w1 = 0, w2 = 0, w3 = 0;
        w0 = __builtin_amdgcn_cvt_pk_fp8_f32(f0.x, f0.y, w0, false);
        w0 = __builtin_amdgcn_cvt_pk_fp8_f32(f0.z, f0.w, w0, true);
        w1 = __builtin_amdgcn_cvt_pk_fp8_f32(f1.x, f1.y, w1, false);
        w1 = __builtin_amdgcn_cvt_pk_fp8_f32(f1.z, f1.w, w1, true);
        w2 = __builtin_amdgcn_cvt_pk_fp8_f32(f2.x, f2.y, w2, false);
        w2 = __builtin_amdgcn_cvt_pk_fp8_f32(f2.z, f2.w, w2, true);
        w3 = __builtin_amdgcn_cvt_pk_fp8_f32(f3.x, f3.y, w3, false);
        w3 = __builtin_amdgcn_cvt_pk_fp8_f32(f3.z, f3.w, w3, true);
        int kc = k0 >> 5;
        int h2 = (k0 >> 4) & 1;
        int4v o = { w0, w1, w2, w3 };
        *(int4v*)(dst + (size_t)kc * 1024 + h2 * 512 + r * 16) = o;
    }
}

// sum of exp2(a[i] * 1/(tau*ln2)) over one accumulator, pairwise tree.
// RAW v_exp_f32: |x| <= ~60, inside the exact range of the HW instruction ->
// bit-identical to libm exp2f here, 1 VALU op instead of OCML's fixup chain.
__device__ __forceinline__ float expsum16(floatx16 a) {
    constexpr float INV_TAU_LN2 = 0.7213475204444817f;  // 1/(tau*ln2), tau=2
    float e[16];
    #pragma unroll
    for (int i = 0; i < 16; ++i)
        e[i] = __builtin_amdgcn_exp2f(a[i] * INV_TAU_LN2);
    float t0 = (e[0] + e[1])  + (e[2] + e[3]);
    float t1 = (e[4] + e[5])  + (e[6] + e[7]);
    float t2 = (e[8] + e[9])  + (e[10] + e[11]);
    float t3 = (e[12] + e[13]) + (e[14] + e[15]);
    return (t0 + t1) + (t2 + t3);
}

// ---- K2: fused fp8 GEMM + lse-pool. V-RESIDENT-IN-REGISTERS structure. ----
// R2 post-mortem: 55% of wall was load-wait (MfmaUtil 46 + VALU 23, stall
// ~1700 cy/iter) and the 6-load/iter pipeline had no register room to deepen.
// Fix: wave tile 64 audio x 64 v. The wave's ENTIRE V operand (2 groups x 12
// k-units = 384 B/lane = 96 VGPRs) is preloaded once and stays in registers;
// the k-loop loads only A (2 x 1KB per iter) with a 4-slot rotating prefetch
// at DISTANCE 3 (~1536 cy coverage vs measured ~1500 cy stall), pinned by
// sched_barrier(0) against compiler sinking. acc[2][2]=64 AGPR; ~225 regs
// total -> 2 waves/SIMD. Block = 4 waves = 4 v-quarters over the SAME 64
// audio rows (A loads get 4-way L1 reuse); exp-partials merged across
// quarters via 1KB LDS before the log (linear in exp-space -> exact).
__global__ __launch_bounds__(256, 2) void gemm_lse_kernel(
        const unsigned char* __restrict__ a8,
        const unsigned char* __restrict__ b8,
        float* __restrict__ out)
{
    __shared__ float ms[4][2][32];   // [v-quarter][a-group][row]

    const int tid  = threadIdx.x;
    const int lane = tid & 63;
    const int vq   = tid >> 6;       // wave = v-quarter (64 v each)

    // XCD-chunked decode (block -> XCD = blockIdx%8): bi tied to XCD
    // => per-XCD L2 set = A(4 bi)=786KB + B(all)=3.1MB ~= 3.9MB <= 4MB.
    int b = blockIdx.x;
    const int xcd   = b & 7;      b >>= 3;
    const int bi_lo = b & 3;      b >>= 2;
    const int ro    = b & 7;      b >>= 3;   // row-oct: 64 audio rows
    const int bj    = b;                      // 0..31
    const int bi    = xcd * 4 + bi_lo;        // 0..31

    const size_t laneoff = (size_t)lane * 16;
    const unsigned char* pa0 = a8 + (size_t)(bi * 16 + ro * 2) * GROUP_BYTES + laneoff;
    const unsigned char* pa1 = pa0 + GROUP_BYTES;
    const unsigned char* pv0 = b8 + (size_t)(bj * 8 + vq * 2) * GROUP_BYTES + laneoff;
    const unsigned char* pv1 = pv0 + GROUP_BYTES;

    // ---- prologue: A prefetch stages 0..2, then full V preload (24 loads).
    // First MFMAs need only stage 0 + Vr[*][0]; later V arrivals hide under
    // the early k-iters' MFMAs (compiler emits counted vmcnt per use).
    long2v Apre[4][2];
    #pragma unroll
    for (int s = 0; s < 3; ++s) {
        Apre[s][0] = *(const long2v*)(pa0 + (size_t)s * 1024);
        Apre[s][1] = *(const long2v*)(pa1 + (size_t)s * 1024);
    }
    long2v Vr[2][NK];
    #pragma unroll
    for (int kc = 0; kc < NK; ++kc) {
        Vr[0][kc] = *(const long2v*)(pv0 + (size_t)kc * 1024);
        Vr[1][kc] = *(const long2v*)(pv1 + (size_t)kc * 1024);
    }

    floatx16 acc[2][2];
    #pragma unroll
    for (int r = 0; r < 2; ++r)
        #pragma unroll
        for (int g = 0; g < 2; ++g)
            acc[r][g] = (floatx16)(0.0f);

    #pragma unroll
    for (int k = 0; k < NK; ++k) {
        // distance-3 A prefetch into the slot freed last iteration
        if (k + 3 < NK) {
            Apre[(k + 3) & 3][0] = *(const long2v*)(pa0 + (size_t)(k + 3) * 1024);
            Apre[(k + 3) & 3][1] = *(const long2v*)(pa1 + (size_t)(k + 3) * 1024);
        }
        __builtin_amdgcn_sched_barrier(0);   // pin: loads stay ABOVE the MFMAs
        // 8 MFMAs, 4 independent 2-chains (V in A-slot, audio in B-slot)
        __builtin_amdgcn_s_setprio(1);
        #pragma unroll
        for (int g = 0; g < 2; ++g) {
            acc[0][g] = __builtin_amdgcn_mfma_f32_32x32x16_fp8_fp8(Vr[g][k].x, Apre[k & 3][0].x, acc[0][g], 0, 0, 0);
            acc[1][g] = __builtin_amdgcn_mfma_f32_32x32x16_fp8_fp8(Vr[g][k].x, Apre[k & 3][1].x, acc[1][g], 0, 0, 0);
        }
        #pragma unroll
        for (int g = 0; g < 2; ++g) {
            acc[0][g] = __builtin_amdgcn_mfma_f32_32x32x16_fp8_fp8(Vr[g][k].y, Apre[k & 3][0].y, acc[0][g], 0, 0, 0);
            acc[1][g] = __builtin_amdgcn_mfma_f32_32x32x16_fp8_fp8(Vr[g][k].y, Apre[k & 3][1].y, acc[1][g], 0, 0, 0);
        }
        __builtin_amdgcn_s_setprio(0);
    }

    // ---- epilogue: per-thread exp-sum over this wave's 64 v ----
    // C/D layout: audio row = (lane&31) within a-group; regs = v indices.
    // (no max needed: |sims/tau| <= ~55 -> exp2 within fp32 range; exact)
    float s0 = expsum16(acc[0][0]) + expsum16(acc[0][1]);
    float s1 = expsum16(acc[1][0]) + expsum16(acc[1][1]);
    s0 += __shfl_xor(s0, 32);    // merge lane>>5 v-halves
    s1 += __shfl_xor(s1, 32);
    if (lane < 32) {
        ms[vq][0][lane] = s0;
        ms[vq][1][lane] = s1;
    }
    __syncthreads();

    // merge the 4 v-quarters (exp-space, linear -> exact), then lse + mean
    if (tid < 64) {
        const int g = tid >> 5, r = tid & 31;
        float e = (ms[0][g][r] + ms[1][g][r]) + (ms[2][g][r] + ms[3][g][r]);
        constexpr float TAU_LN2 = 1.3862943611198906f;  // tau*ln2 (v_log_f32 = log2)
        float lse = TAU_LN2 * __builtin_amdgcn_logf(e);
        #pragma unroll
        for (int m = 1; m < 64; m <<= 1) lse += __shfl_xor(lse, m);
        if (tid == 0)
            atomicAdd(&out[bi * 32 + bj], lse * (1.0f / Na));  // 8 adds/output (ro)
    }
}

extern "C" void kernel_launch(void* const* d_in, const int* in_sizes, int n_in,
                              void* d_out, int out_size, void* d_ws, size_t ws_size,
                              hipStream_t stream) {
    const float* audio  = (const float*)d_in[0];
    const float* visual = (const float*)d_in[1];
    float* out = (float*)d_out;

    unsigned char* a8 = (unsigned char*)d_ws;                        // 6.29 MB fp8 A
    unsigned char* b8 = a8 + (size_t)AGROUPS * GROUP_BYTES;          // +3.15 MB fp8 B

    convert_fp8_kernel<<<dim3(AGROUPS + BGROUPS), dim3(256), 0, stream>>>(
        audio, visual, a8, b8, out);
    // grid: 8192 blocks x 4 waves = 32768 waves
    //     = 32 bi x 32 bj x 8 row-octs, block = 64 audio rows x 256 v
    gemm_lse_kernel<<<dim3(8192), dim3(256), 0, stream>>>(a8, b8, out);
}

// Round 4
// 151.767 us; speedup vs baseline: 1.0734x; 1.0734x over previous
//
#include <hip/hip_runtime.h>

// ---- problem constants (fixed by reference setup_inputs) ----
constexpr int B_  = 32;
constexpr int Na  = 512;
constexpr int Nv  = 256;
constexpr int D   = 384;

constexpr int NK  = D / 32;    // 12 k-chunks of 32

// fp8 operand regions: one 32-row group x 384 k = 12 chunks x 1 KB = 12 KB.
// Unit (group, kc) internal layout: byte = h2*512 + r*16 + j, holding
// value[row r][k = kc*32 + h2*16 + j]  (r = lane&31, k-half h2 = lane>>5).
// The (lane,byte)->k permutation is IDENTICAL for the MFMA A-slot and B-slot,
// so the contraction is exact for either operand role -> operands swappable.
constexpr int AGROUPS = B_ * 16;   // 512 groups (bi*16+rg), rows linear
constexpr int BGROUPS = B_ * 8;    // 256 groups (bj*8+cg), rows linear
constexpr size_t GROUP_BYTES = 12 * 1024;

typedef long  long2v   __attribute__((ext_vector_type(2)));
typedef int   int4v    __attribute__((ext_vector_type(4)));
typedef float floatx16 __attribute__((ext_vector_type(16)));

// ---- K1: zero output + fp32 -> fp8(e4m3 OCP) conversion, BOTH sides coalesced ----
__global__ void convert_fp8_kernel(const float* __restrict__ a, const float* __restrict__ v,
                                   unsigned char* __restrict__ a8,
                                   unsigned char* __restrict__ b8,
                                   float* __restrict__ out) {
    int gid = blockIdx.x * blockDim.x + threadIdx.x;
    if (gid < B_ * B_) out[gid] = 0.0f;    // d_out is poisoned before every launch

    const float* src;
    unsigned char* dst;
    int blk = blockIdx.x;
    if (blk < AGROUPS) {                       // A rows are linear: group*32 + r
        src = a + (size_t)blk * 32 * D;
        dst = a8 + (size_t)blk * GROUP_BYTES;
    } else {
        int b2 = blk - AGROUPS;
        src = v + (size_t)b2 * 32 * D;
        dst = b8 + (size_t)b2 * GROUP_BYTES;
    }
    const int t = threadIdx.x;
    const int r = t >> 3, q = t & 7;

    #pragma unroll
    for (int p = 0; p < 3; ++p) {
        int k0 = p * 128 + q * 16;
        const float4* s4 = (const float4*)(src + (size_t)r * D + k0);
        float4 f0 = s4[0], f1 = s4[1], f2 = s4[2], f3 = s4[3];
        int w0 = 0, w1 = 0, w2 = 0, w3 = 0;
        w0 = __builtin_amdgcn_cvt_pk_fp8_f32(f0.x, f0.y, w0, false);
        w0 = __builtin_amdgcn_cvt_pk_fp8_f32(f0.z, f0.w, w0, true);
        w1 = __builtin_amdgcn_cvt_pk_fp8_f32(f1.x, f1.y, w1, false);
        w1 = __builtin_amdgcn_cvt_pk_fp8_f32(f1.z, f1.w, w1, true);
        w2 = __builtin_amdgcn_cvt_pk_fp8_f32(f2.x, f2.y, w2, false);
        w2 = __builtin_amdgcn_cvt_pk_fp8_f32(f2.z, f2.w, w2, true);
        w3 = __builtin_amdgcn_cvt_pk_fp8_f32(f3.x, f3.y, w3, false);
        w3 = __builtin_amdgcn_cvt_pk_fp8_f32(f3.z, f3.w, w3, true);
        int kc = k0 >> 5;
        int h2 = (k0 >> 4) & 1;
        int4v o = { w0, w1, w2, w3 };
        *(int4v*)(dst + (size_t)kc * 1024 + h2 * 512 + r * 16) = o;
    }
}

// sum of exp2(a[i] * 1/(tau*ln2)) over one accumulator, pairwise tree.
// RAW v_exp_f32: |x| <= ~60, inside the exact range of the HW instruction ->
// bit-identical to libm exp2f here, 1 VALU op instead of OCML's fixup chain.
__device__ __forceinline__ float expsum16(floatx16 a) {
    constexpr float INV_TAU_LN2 = 0.7213475204444817f;  // 1/(tau*ln2), tau=2
    float e[16];
    #pragma unroll
    for (int i = 0; i < 16; ++i)
        e[i] = __builtin_amdgcn_exp2f(a[i] * INV_TAU_LN2);
    float t0 = (e[0] + e[1])  + (e[2] + e[3]);
    float t1 = (e[4] + e[5])  + (e[6] + e[7]);
    float t2 = (e[8] + e[9])  + (e[10] + e[11]);
    float t3 = (e[12] + e[13]) + (e[14] + e[15]);
    return (t0 + t1) + (t2 + t3);
}

// ---- K2: fused fp8 GEMM + lse-pool. 4-WAVES/SIMD OCCUPANCY structure. ----
// R3 post-mortem: all reg-pipeline variants pinned at MfmaUtil 43-47 with 2
// waves/SIMD -- the allocator sinks "preloads" to distance 0, exposing
// ~600-1200 cy of load latency per iter that one other wave can't cover.
// Fix is TLP, not scheduling: shrink the wave tile to 64 audio x 64 v so
// acc[2][2]=64 AGPR + 2-slot operand buffers (~120 unified regs) fit FOUR
// waves/SIMD. Then even distance-0 loads are covered: per-iter window =
// 4 x 272 cy MFMA >= loaded L1/L2 latency. Block = 4 waves on the SAME 64
// audio rows (A loads identical across waves -> L1 hits), disjoint 64-v
// quarters; exp-partials merged via 1 KB LDS (linear in exp-space -> exact).
// L1 demand at full MFMA saturation: 4KB/272cy/SIMD = 59 B/cy/CU, just under
// the ~64 B/cy L1 port.
__global__ __launch_bounds__(256, 4) void gemm_lse_kernel(
        const unsigned char* __restrict__ a8,
        const unsigned char* __restrict__ b8,
        float* __restrict__ out)
{
    __shared__ float ms[4][2][32];   // [v-quarter][a-group][row]

    const int tid  = threadIdx.x;
    const int lane = tid & 63;
    const int vq   = tid >> 6;       // wave = v-quarter (64 v each)

    // XCD-chunked decode (block -> XCD = blockIdx%8): bi tied to XCD
    // => per-XCD L2 set = A(4 bi)=786KB + B(all)=3.1MB ~= 3.9MB <= 4MB.
    int b = blockIdx.x;
    const int xcd   = b & 7;      b >>= 3;
    const int bi_lo = b & 3;      b >>= 2;
    const int ro    = b & 7;      b >>= 3;   // row-oct: 64 audio rows
    const int bj    = b;                      // 0..31
    const int bi    = xcd * 4 + bi_lo;        // 0..31

    const size_t laneoff = (size_t)lane * 16;
    const unsigned char* pa0 = a8 + (size_t)(bi * 16 + ro * 2) * GROUP_BYTES + laneoff;
    const unsigned char* pa1 = pa0 + GROUP_BYTES;
    const unsigned char* pv0 = b8 + (size_t)(bj * 8 + vq * 2) * GROUP_BYTES + laneoff;
    const unsigned char* pv1 = pv0 + GROUP_BYTES;

    // distance-1 double-buffered operands (2 A-groups + 2 V-groups = 4 KB/iter)
    long2v Ab[2][2], Vb[2][2];
    Ab[0][0] = *(const long2v*)pa0;
    Ab[0][1] = *(const long2v*)pa1;
    Vb[0][0] = *(const long2v*)pv0;
    Vb[0][1] = *(const long2v*)pv1;

    floatx16 acc[2][2];
    #pragma unroll
    for (int ag = 0; ag < 2; ++ag)
        #pragma unroll
        for (int vg = 0; vg < 2; ++vg)
            acc[ag][vg] = (floatx16)(0.0f);

    #pragma unroll
    for (int k = 0; k < NK; ++k) {
        const int cur = k & 1, nxt = cur ^ 1;
        if (k + 1 < NK) {
            const size_t o = (size_t)(k + 1) * 1024;
            Ab[nxt][0] = *(const long2v*)(pa0 + o);
            Ab[nxt][1] = *(const long2v*)(pa1 + o);
            Vb[nxt][0] = *(const long2v*)(pv0 + o);
            Vb[nxt][1] = *(const long2v*)(pv1 + o);
        }
        __builtin_amdgcn_sched_barrier(0);   // loads issue above the MFMA cluster
        // 8 MFMAs = 4 independent 2-chains (V in A-slot, audio in B-slot)
        __builtin_amdgcn_s_setprio(1);
        #pragma unroll
        for (int vg = 0; vg < 2; ++vg) {
            acc[0][vg] = __builtin_amdgcn_mfma_f32_32x32x16_fp8_fp8(Vb[cur][vg].x, Ab[cur][0].x, acc[0][vg], 0, 0, 0);
            acc[1][vg] = __builtin_amdgcn_mfma_f32_32x32x16_fp8_fp8(Vb[cur][vg].x, Ab[cur][1].x, acc[1][vg], 0, 0, 0);
        }
        #pragma unroll
        for (int vg = 0; vg < 2; ++vg) {
            acc[0][vg] = __builtin_amdgcn_mfma_f32_32x32x16_fp8_fp8(Vb[cur][vg].y, Ab[cur][0].y, acc[0][vg], 0, 0, 0);
            acc[1][vg] = __builtin_amdgcn_mfma_f32_32x32x16_fp8_fp8(Vb[cur][vg].y, Ab[cur][1].y, acc[1][vg], 0, 0, 0);
        }
        __builtin_amdgcn_s_setprio(0);
        __builtin_amdgcn_sched_barrier(0);
    }

    // ---- epilogue: per-thread exp-sum over this wave's 64 v ----
    // C/D layout: audio row = (lane&31) within a-group; regs = v indices.
    // (no max needed: |sims/tau| <= ~55 -> exp2 within fp32 range; exact)
    float s0 = expsum16(acc[0][0]) + expsum16(acc[0][1]);
    float s1 = expsum16(acc[1][0]) + expsum16(acc[1][1]);
    s0 += __shfl_xor(s0, 32);    // merge lane>>5 v-halves
    s1 += __shfl_xor(s1, 32);
    if (lane < 32) {
        ms[vq][0][lane] = s0;
        ms[vq][1][lane] = s1;
    }
    __syncthreads();

    // merge the 4 v-quarters (exp-space, linear -> exact), then lse + mean
    if (tid < 64) {
        const int g = tid >> 5, r = tid & 31;
        float e = (ms[0][g][r] + ms[1][g][r]) + (ms[2][g][r] + ms[3][g][r]);
        constexpr float TAU_LN2 = 1.3862943611198906f;  // tau*ln2 (v_log_f32 = log2)
        float lse = TAU_LN2 * __builtin_amdgcn_logf(e);
        #pragma unroll
        for (int m = 1; m < 64; m <<= 1) lse += __shfl_xor(lse, m);
        if (tid == 0)
            atomicAdd(&out[bi * 32 + bj], lse * (1.0f / Na));  // 8 adds/output (ro)
    }
}

extern "C" void kernel_launch(void* const* d_in, const int* in_sizes, int n_in,
                              void* d_out, int out_size, void* d_ws, size_t ws_size,
                              hipStream_t stream) {
    const float* audio  = (const float*)d_in[0];
    const float* visual = (const float*)d_in[1];
    float* out = (float*)d_out;

    unsigned char* a8 = (unsigned char*)d_ws;                        // 6.29 MB fp8 A
    unsigned char* b8 = a8 + (size_t)AGROUPS * GROUP_BYTES;          // +3.15 MB fp8 B

    convert_fp8_kernel<<<dim3(AGROUPS + BGROUPS), dim3(256), 0, stream>>>(
        audio, visual, a8, b8, out);
    // grid: 8192 blocks x 4 waves = 32768 waves
    //     = 32 bi x 32 bj x 8 row-octs, block = 64 audio rows x 256 v
    gemm_lse_kernel<<<dim3(8192), dim3(256), 0, stream>>>(a8, b8, out);
}

// Round 5
// 131.669 us; speedup vs baseline: 1.2372x; 1.1526x over previous
//
#include <hip/hip_runtime.h>

// ---- problem constants (fixed by reference setup_inputs) ----
constexpr int B_  = 32;
constexpr int Na  = 512;
constexpr int Nv  = 256;
constexpr int D   = 384;

constexpr int NK2 = D / 64;    // 6 k-chunks of 64 (one scaled MFMA each)

// fp8 operand regions: one 32-row group x 384 k = 12 chunks x 1 KB = 12 KB.
// Unit (group, kc) internal layout: byte = h2*512 + r*16 + j, holding
// value[row r][k = kc*32 + h2*16 + j]  (r = lane&31, k-half h2 = lane>>5).
// The (lane,byte)->k packing is IDENTICAL for the A-slot and B-slot operands
// (we build both buffers), so the contraction is exact for any consistent
// packing -> exact under operand swap AND under the K=64 scaled MFMA, where
// each lane takes unit kc's 16B into regs0-3 and unit kc+1's into regs4-7
// for BOTH operands. Scales fixed at 1.0 (e8m0 0x7F) -> products identical
// to the non-scaled fp8 MFMA.
constexpr int AGROUPS = B_ * 16;   // 512 groups (bi*16+rg), rows linear
constexpr int BGROUPS = B_ * 8;    // 256 groups (bj*8+cg), rows linear
constexpr size_t GROUP_BYTES = 12 * 1024;
constexpr int SCALE_ONE = 0x7F7F7F7F;   // e8m0 127 = 2^0 in every byte

typedef int   int4v    __attribute__((ext_vector_type(4)));
typedef int   int8v    __attribute__((ext_vector_type(8)));
typedef float floatx16 __attribute__((ext_vector_type(16)));

// ---- K1: zero output + fp32 -> fp8(e4m3 OCP) conversion, BOTH sides coalesced ----
__global__ void convert_fp8_kernel(const float* __restrict__ a, const float* __restrict__ v,
                                   unsigned char* __restrict__ a8,
                                   unsigned char* __restrict__ b8,
                                   float* __restrict__ out) {
    int gid = blockIdx.x * blockDim.x + threadIdx.x;
    if (gid < B_ * B_) out[gid] = 0.0f;    // d_out is poisoned before every launch

    const float* src;
    unsigned char* dst;
    int blk = blockIdx.x;
    if (blk < AGROUPS) {                       // A rows are linear: group*32 + r
        src = a + (size_t)blk * 32 * D;
        dst = a8 + (size_t)blk * GROUP_BYTES;
    } else {
        int b2 = blk - AGROUPS;
        src = v + (size_t)b2 * 32 * D;
        dst = b8 + (size_t)b2 * GROUP_BYTES;
    }
    const int t = threadIdx.x;
    const int r = t >> 3, q = t & 7;

    #pragma unroll
    for (int p = 0; p < 3; ++p) {
        int k0 = p * 128 + q * 16;
        const float4* s4 = (const float4*)(src + (size_t)r * D + k0);
        float4 f0 = s4[0], f1 = s4[1], f2 = s4[2], f3 = s4[3];
        int w0 = 0, w1 = 0, w2 = 0, w3 = 0;
        w0 = __builtin_amdgcn_cvt_pk_fp8_f32(f0.x, f0.y, w0, false);
        w0 = __builtin_amdgcn_cvt_pk_fp8_f32(f0.z, f0.w, w0, true);
        w1 = __builtin_amdgcn_cvt_pk_fp8_f32(f1.x, f1.y, w1, false);
        w1 = __builtin_amdgcn_cvt_pk_fp8_f32(f1.z, f1.w, w1, true);
        w2 = __builtin_amdgcn_cvt_pk_fp8_f32(f2.x, f2.y, w2, false);
        w2 = __builtin_amdgcn_cvt_pk_fp8_f32(f2.z, f2.w, w2, true);
        w3 = __builtin_amdgcn_cvt_pk_fp8_f32(f3.x, f3.y, w3, false);
        w3 = __builtin_amdgcn_cvt_pk_fp8_f32(f3.z, f3.w, w3, true);
        int kc = k0 >> 5;
        int h2 = (k0 >> 4) & 1;
        int4v o = { w0, w1, w2, w3 };
        *(int4v*)(dst + (size_t)kc * 1024 + h2 * 512 + r * 16) = o;
    }
}

// sum of exp2(a[i] * 1/(tau*ln2)) over one accumulator, pairwise tree.
// RAW v_exp_f32: |x| <= ~60, inside the exact range of the HW instruction ->
// bit-identical to libm exp2f here, 1 VALU op instead of OCML's fixup chain.
__device__ __forceinline__ float expsum16(floatx16 a) {
    constexpr float INV_TAU_LN2 = 0.7213475204444817f;  // 1/(tau*ln2), tau=2
    float e[16];
    #pragma unroll
    for (int i = 0; i < 16; ++i)
        e[i] = __builtin_amdgcn_exp2f(a[i] * INV_TAU_LN2);
    float t0 = (e[0] + e[1])  + (e[2] + e[3]);
    float t1 = (e[4] + e[5])  + (e[6] + e[7]);
    float t2 = (e[8] + e[9])  + (e[10] + e[11]);
    float t3 = (e[12] + e[13]) + (e[14] + e[15]);
    return (t0 + t1) + (t2 + t3);
}

__device__ __forceinline__ int8v mk8(int4v lo, int4v hi) {
    int8v r;
    r[0] = lo[0]; r[1] = lo[1]; r[2] = lo[2]; r[3] = lo[3];
    r[4] = hi[0]; r[5] = hi[1]; r[6] = hi[2]; r[7] = hi[3];
    return r;
}

// ---- K2: fused MX-scaled fp8 GEMM (32x32x64, scales=1.0) + lse-pool ----
// R4 post-mortem: dur (88-90us) and MfmaUtil (43-48%) are INVARIANT across
// 2x occupancy and 1.5x byte-traffic changes -> the limiter scales with the
// MFMA work itself in this direct-from-global regime. Discriminator: the
// scaled 32x32x64 f8f6f4 MFMA does 4x K in ~1.9x pipe cycles (4686 vs 2190
// TF ubench), halving total MFMA pipe time at IDENTICAL loads/bytes/structure.
// If the wall tracks MFMA work -> ~2x. If it's the load path -> unchanged and
// MfmaUtil drops to ~25% (then: LDS-stage A next).
// Wave tile 64 audio x 64 v, acc[2][2] = 64 AGPR; operands double-buffered
// (Ab/Vb[2][2] int8v = 64 VGPR); ~140 unified regs -> 3 waves/SIMD.
__global__ __launch_bounds__(256, 3) void gemm_lse_kernel(
        const unsigned char* __restrict__ a8,
        const unsigned char* __restrict__ b8,
        float* __restrict__ out)
{
    __shared__ float ms[4][2][32];   // [v-quarter][a-group][row]

    const int tid  = threadIdx.x;
    const int lane = tid & 63;
    const int vq   = tid >> 6;       // wave = v-quarter (64 v each)

    // XCD-chunked decode (block -> XCD = blockIdx%8): bi tied to XCD
    // => per-XCD L2 set = A(4 bi)=786KB + B(all)=3.1MB ~= 3.9MB <= 4MB.
    int b = blockIdx.x;
    const int xcd   = b & 7;      b >>= 3;
    const int bi_lo = b & 3;      b >>= 2;
    const int ro    = b & 7;      b >>= 3;   // row-oct: 64 audio rows
    const int bj    = b;                      // 0..31
    const int bi    = xcd * 4 + bi_lo;        // 0..31

    const size_t laneoff = (size_t)lane * 16;
    const unsigned char* pa0 = a8 + (size_t)(bi * 16 + ro * 2) * GROUP_BYTES + laneoff;
    const unsigned char* pa1 = pa0 + GROUP_BYTES;
    const unsigned char* pv0 = b8 + (size_t)(bj * 8 + vq * 2) * GROUP_BYTES + laneoff;
    const unsigned char* pv1 = pv0 + GROUP_BYTES;

    // distance-1 double-buffered 32B operands (2 A-groups + 2 V-groups = 8 KB/iter)
    int8v Ab[2][2], Vb[2][2];
    Ab[0][0] = mk8(*(const int4v*)pa0, *(const int4v*)(pa0 + 1024));
    Ab[0][1] = mk8(*(const int4v*)pa1, *(const int4v*)(pa1 + 1024));
    Vb[0][0] = mk8(*(const int4v*)pv0, *(const int4v*)(pv0 + 1024));
    Vb[0][1] = mk8(*(const int4v*)pv1, *(const int4v*)(pv1 + 1024));

    floatx16 acc[2][2];
    #pragma unroll
    for (int ag = 0; ag < 2; ++ag)
        #pragma unroll
        for (int vg = 0; vg < 2; ++vg)
            acc[ag][vg] = (floatx16)(0.0f);

    #pragma unroll
    for (int k = 0; k < NK2; ++k) {
        const int cur = k & 1, nxt = cur ^ 1;
        if (k + 1 < NK2) {
            const size_t o = (size_t)(k + 1) * 2048;
            Ab[nxt][0] = mk8(*(const int4v*)(pa0 + o), *(const int4v*)(pa0 + o + 1024));
            Ab[nxt][1] = mk8(*(const int4v*)(pa1 + o), *(const int4v*)(pa1 + o + 1024));
            Vb[nxt][0] = mk8(*(const int4v*)(pv0 + o), *(const int4v*)(pv0 + o + 1024));
            Vb[nxt][1] = mk8(*(const int4v*)(pv1 + o), *(const int4v*)(pv1 + o + 1024));
        }
        __builtin_amdgcn_sched_barrier(0);   // loads issue above the MFMA cluster
        // 4 independent scaled MFMAs (V in A-slot, audio in B-slot; fp8/fp8,
        // scales = 1.0 -> numerically identical to non-scaled fp8 MFMA)
        __builtin_amdgcn_s_setprio(1);
        #pragma unroll
        for (int vg = 0; vg < 2; ++vg) {
            acc[0][vg] = __builtin_amdgcn_mfma_scale_f32_32x32x64_f8f6f4(
                Vb[cur][vg], Ab[cur][0], acc[0][vg], 0, 0, 0, SCALE_ONE, 0, SCALE_ONE);
            acc[1][vg] = __builtin_amdgcn_mfma_scale_f32_32x32x64_f8f6f4(
                Vb[cur][vg], Ab[cur][1], acc[1][vg], 0, 0, 0, SCALE_ONE, 0, SCALE_ONE);
        }
        __builtin_amdgcn_s_setprio(0);
        __builtin_amdgcn_sched_barrier(0);
    }

    // ---- epilogue: per-thread exp-sum over this wave's 64 v ----
    // C/D layout is shape-determined (same as 32x32x16): audio row = (lane&31)
    // within a-group; regs = v indices.
    // (no max needed: |sims/tau| <= ~55 -> exp2 within fp32 range; exact)
    float s0 = expsum16(acc[0][0]) + expsum16(acc[0][1]);
    float s1 = expsum16(acc[1][0]) + expsum16(acc[1][1]);
    s0 += __shfl_xor(s0, 32);    // merge lane>>5 v-halves
    s1 += __shfl_xor(s1, 32);
    if (lane < 32) {
        ms[vq][0][lane] = s0;
        ms[vq][1][lane] = s1;
    }
    __syncthreads();

    // merge the 4 v-quarters (exp-space, linear -> exact), then lse + mean
    if (tid < 64) {
        const int g = tid >> 5, r = tid & 31;
        float e = (ms[0][g][r] + ms[1][g][r]) + (ms[2][g][r] + ms[3][g][r]);
        constexpr float TAU_LN2 = 1.3862943611198906f;  // tau*ln2 (v_log_f32 = log2)
        float lse = TAU_LN2 * __builtin_amdgcn_logf(e);
        #pragma unroll
        for (int m = 1; m < 64; m <<= 1) lse += __shfl_xor(lse, m);
        if (tid == 0)
            atomicAdd(&out[bi * 32 + bj], lse * (1.0f / Na));  // 8 adds/output (ro)
    }
}

extern "C" void kernel_launch(void* const* d_in, const int* in_sizes, int n_in,
                              void* d_out, int out_size, void* d_ws, size_t ws_size,
                              hipStream_t stream) {
    const float* audio  = (const float*)d_in[0];
    const float* visual = (const float*)d_in[1];
    float* out = (float*)d_out;

    unsigned char* a8 = (unsigned char*)d_ws;                        // 6.29 MB fp8 A
    unsigned char* b8 = a8 + (size_t)AGROUPS * GROUP_BYTES;          // +3.15 MB fp8 B

    convert_fp8_kernel<<<dim3(AGROUPS + BGROUPS), dim3(256), 0, stream>>>(
        audio, visual, a8, b8, out);
    // grid: 8192 blocks x 4 waves = 32768 waves
    //     = 32 bi x 32 bj x 8 row-octs, block = 64 audio rows x 256 v
    gemm_lse_kernel<<<dim3(8192), dim3(256), 0, stream>>>(a8, b8, out);
}

// Round 6
// 128.585 us; speedup vs baseline: 1.2669x; 1.0240x over previous
//
#include <hip/hip_runtime.h>

// ---- problem constants (fixed by reference setup_inputs) ----
constexpr int B_  = 32;
constexpr int Na  = 512;
constexpr int Nv  = 256;
constexpr int D   = 384;

constexpr int NK2 = D / 64;    // 6 k-chunks of 64 (one scaled MFMA each)

// fp8 operand regions, one 32-row group x 384 k = 12 KB per group.
// A-side (a8) layout (unchanged): unit kc (1 KB): byte = h2*512 + r*16 + j
//   holding value[row r][k = kc*32 + h2*16 + j]. MFMA lane l reads 16 B at
//   l*16 (r=l&31, h2=l>>5). K=64 operand = unit 2q2 (regs0-3) then unit
//   2q2+1 (regs4-7) -> two 1-KB-apart ds_read_b128, both lane-contiguous
//   (conflict-free baseline pattern).
// V-side (b8) NEW layout: k64-unit q2 (2 KB): lane l's 32 B contiguous at
//   l*32 = [unit 2q2's 16B at l*16][unit 2q2+1's 16B at l*16] -> ONE int8v
//   global deref (2 coalesced dwordx4), no register shuffling.
// The (lane,byte)->k packing is IDENTICAL for A-slot and B-slot operands,
// so the contraction is exact under operand swap; scales = 1.0 (e8m0 0x7F)
// make the scaled MFMA numerically identical to non-scaled fp8.
constexpr int AGROUPS = B_ * 16;   // 512 groups (bi*16+rg), rows linear
constexpr int BGROUPS = B_ * 8;    // 256 groups (bj*8+cg), rows linear
constexpr size_t GROUP_BYTES = 12 * 1024;
constexpr int SCALE_ONE = 0x7F7F7F7F;   // e8m0 127 = 2^0 in every byte

typedef int   int4v    __attribute__((ext_vector_type(4)));
typedef int   int8v    __attribute__((ext_vector_type(8)));
typedef float floatx16 __attribute__((ext_vector_type(16)));

// 16B-per-lane async global->LDS (lane i writes LDS slot base + i*16)
__device__ __forceinline__ void async_load16(const void* g, void* l) {
    __builtin_amdgcn_global_load_lds(
        (const __attribute__((address_space(1))) unsigned int*)g,
        (__attribute__((address_space(3))) unsigned int*)l,
        16, 0, 0);
}

// ---- K1: zero output + fp32 -> fp8(e4m3 OCP) conversion, BOTH sides coalesced ----
__global__ void convert_fp8_kernel(const float* __restrict__ a, const float* __restrict__ v,
                                   unsigned char* __restrict__ a8,
                                   unsigned char* __restrict__ b8,
                                   float* __restrict__ out) {
    int gid = blockIdx.x * blockDim.x + threadIdx.x;
    if (gid < B_ * B_) out[gid] = 0.0f;    // d_out is poisoned before every launch

    const float* src;
    unsigned char* dst;
    int blk = blockIdx.x;
    const bool isA = blk < AGROUPS;
    if (isA) {                                 // A rows are linear: group*32 + r
        src = a + (size_t)blk * 32 * D;
        dst = a8 + (size_t)blk * GROUP_BYTES;
    } else {
        int b2 = blk - AGROUPS;
        src = v + (size_t)b2 * 32 * D;
        dst = b8 + (size_t)b2 * GROUP_BYTES;
    }
    const int t = threadIdx.x;
    const int r = t >> 3, q = t & 7;

    #pragma unroll
    for (int p = 0; p < 3; ++p) {
        int k0 = p * 128 + q * 16;
        const float4* s4 = (const float4*)(src + (size_t)r * D + k0);
        float4 f0 = s4[0], f1 = s4[1], f2 = s4[2], f3 = s4[3];
        int w0 = 0, w1 = 0, w2 = 0, w3 = 0;
        w0 = __builtin_amdgcn_cvt_pk_fp8_f32(f0.x, f0.y, w0, false);
        w0 = __builtin_amdgcn_cvt_pk_fp8_f32(f0.z, f0.w, w0, true);
        w1 = __builtin_amdgcn_cvt_pk_fp8_f32(f1.x, f1.y, w1, false);
        w1 = __builtin_amdgcn_cvt_pk_fp8_f32(f1.z, f1.w, w1, true);
        w2 = __builtin_amdgcn_cvt_pk_fp8_f32(f2.x, f2.y, w2, false);
        w2 = __builtin_amdgcn_cvt_pk_fp8_f32(f2.z, f2.w, w2, true);
        w3 = __builtin_amdgcn_cvt_pk_fp8_f32(f3.x, f3.y, w3, false);
        w3 = __builtin_amdgcn_cvt_pk_fp8_f32(f3.z, f3.w, w3, true);
        int kc = k0 >> 5;
        int h2 = (k0 >> 4) & 1;
        size_t off;
        if (isA) {
            off = (size_t)kc * 1024 + h2 * 512 + r * 16;            // old layout
        } else {
            int q2 = kc >> 1, u = kc & 1, l = r + 32 * h2;          // lane-32B units
            off = (size_t)q2 * 2048 + l * 32 + u * 16;
        }
        int4v o = { w0, w1, w2, w3 };
        *(int4v*)(dst + off) = o;   // wave's 64 stores still tile full 64B lines
    }
}

// sum of exp2(a[i] * 1/(tau*ln2)) over one accumulator, pairwise tree.
// RAW v_exp_f32: |x| <= ~60, inside the exact range of the HW instruction.
__device__ __forceinline__ float expsum16(floatx16 a) {
    constexpr float INV_TAU_LN2 = 0.7213475204444817f;  // 1/(tau*ln2), tau=2
    float e[16];
    #pragma unroll
    for (int i = 0; i < 16; ++i)
        e[i] = __builtin_amdgcn_exp2f(a[i] * INV_TAU_LN2);
    float t0 = (e[0] + e[1])  + (e[2] + e[3]);
    float t1 = (e[4] + e[5])  + (e[6] + e[7]);
    float t2 = (e[8] + e[9])  + (e[10] + e[11]);
    float t3 = (e[12] + e[13]) + (e[14] + e[15]);
    return (t0 + t1) + (t2 + t3);
}

// ---- K2: fused MX-scaled fp8 GEMM + lse-pool. VMEM-PORT-DEDUPE structure. ----
// R5 post-mortem: the invariant ~40us residual = VMEM return port (~64 B/cy/CU;
// L1 hits cost the port like misses). R5 pushed 1.84 GB of dwordx4 returns =
// 47us of port time. Fix: block = 8 waves, tile 128 audio x 256 v; A (4 groups,
// 48 KB) staged to LDS ONCE whole-K (one barrier total, no k-loop staging), so
// A's port cost is per-BLOCK not per-wave. V stays per-wave direct-to-VGPR
// (irreducible). Port total: V 786 MB + A 98 MB = 884 MB ~= 22.5us ~ MFMA floor
// (21us). LDS read demand = A only = 64 B/cy/CU (half port), conflict-free
// (lane*16-stride b128 reads). Wave tile 64x64: acc[2][2] = 64 AGPR; V int8v
// derefs (new b8 packing) avoid register shuffling; ~50 arch VGPR ->
// launch_bounds(512,4) targets 16 waves/CU.
__global__ __launch_bounds__(512, 4) void gemm_lse_kernel(
        const unsigned char* __restrict__ a8,
        const unsigned char* __restrict__ b8,
        float* __restrict__ out)
{
    __shared__ unsigned char ldsA[48 * 1024];   // block's 4 A-groups, whole K
    __shared__ float ms[4][4][32];              // [v-quarter][a-group][row]

    const int tid  = threadIdx.x;
    const int lane = tid & 63;
    const int wv   = tid >> 6;       // 8 waves
    const int wm   = wv >> 2;        // audio half (64 rows = groups 2wm,2wm+1)
    const int wn   = wv & 3;         // v quarter (64 v = groups 2wn,2wn+1)

    // XCD-chunked decode: bi tied to blockIdx%8 => per-XCD L2 set =
    // A(4 bi) 786KB + B(all) 3.1MB ~= 3.9MB <= 4MB.
    int b = blockIdx.x;
    const int xcd   = b & 7;      b >>= 3;
    const int bi_lo = b & 3;      b >>= 2;
    const int rb    = b & 3;      b >>= 2;   // row-block: 128 audio rows
    const int bj    = b;                      // 0..31
    const int bi    = xcd * 4 + bi_lo;        // 0..31

    // ---- stage A once: 48 contiguous KB (groups bi*16+rb*4 .. +3) ----
    const unsigned char* asrc = a8 + (size_t)(bi * 16 + rb * 4) * GROUP_BYTES
                                   + (size_t)lane * 16;
    #pragma unroll
    for (int i = 0; i < 6; ++i) {
        const int u = wv * 6 + i;            // 48 x 1KB units, 6 per wave
        async_load16(asrc + (size_t)u * 1024, ldsA + u * 1024);
    }
    __syncthreads();   // the ONLY staging barrier (A is static for the block)

    const unsigned char* pv0 = b8 + (size_t)(bj * 8 + wn * 2) * GROUP_BYTES
                                  + (size_t)lane * 32;
    const unsigned char* pv1 = pv0 + GROUP_BYTES;
    const unsigned char* la  = ldsA + (size_t)(2 * wm) * GROUP_BYTES
                                    + (size_t)lane * 16;

    floatx16 acc[2][2];   // [audio group][v group]
    #pragma unroll
    for (int ag = 0; ag < 2; ++ag)
        #pragma unroll
        for (int vg = 0; vg < 2; ++vg)
            acc[ag][vg] = (floatx16)(0.0f);

    #pragma unroll
    for (int q2 = 0; q2 < NK2; ++q2) {
        // V: one int8v deref each = 2 coalesced dwordx4 into an 8-tuple
        int8v V0 = *(const int8v*)(pv0 + (size_t)q2 * 2048);
        int8v V1 = *(const int8v*)(pv1 + (size_t)q2 * 2048);
        // A: k64 operand = units 2q2 (lo) and 2q2+1 (hi), lane-contiguous reads
        int4v a0lo = *(const int4v*)(la + (size_t)q2 * 2048);
        int4v a0hi = *(const int4v*)(la + (size_t)q2 * 2048 + 1024);
        int4v a1lo = *(const int4v*)(la + GROUP_BYTES + (size_t)q2 * 2048);
        int4v a1hi = *(const int4v*)(la + GROUP_BYTES + (size_t)q2 * 2048 + 1024);
        int8v A0 = __builtin_shufflevector(a0lo, a0hi, 0, 1, 2, 3, 4, 5, 6, 7);
        int8v A1 = __builtin_shufflevector(a1lo, a1hi, 0, 1, 2, 3, 4, 5, 6, 7);
        // 4 independent scaled MFMAs (V in A-slot, audio in B-slot)
        __builtin_amdgcn_s_setprio(1);
        acc[0][0] = __builtin_amdgcn_mfma_scale_f32_32x32x64_f8f6f4(
            V0, A0, acc[0][0], 0, 0, 0, SCALE_ONE, 0, SCALE_ONE);
        acc[0][1] = __builtin_amdgcn_mfma_scale_f32_32x32x64_f8f6f4(
            V1, A0, acc[0][1], 0, 0, 0, SCALE_ONE, 0, SCALE_ONE);
        acc[1][0] = __builtin_amdgcn_mfma_scale_f32_32x32x64_f8f6f4(
            V0, A1, acc[1][0], 0, 0, 0, SCALE_ONE, 0, SCALE_ONE);
        acc[1][1] = __builtin_amdgcn_mfma_scale_f32_32x32x64_f8f6f4(
            V1, A1, acc[1][1], 0, 0, 0, SCALE_ONE, 0, SCALE_ONE);
        __builtin_amdgcn_s_setprio(0);
    }

    // ---- epilogue: per-thread exp-sum over this wave's 64 v ----
    // C/D layout (shape-determined): audio row = lane&31 within a-group;
    // regs & lane>>5 = v indices. (no max: |sims/tau| <= ~55 -> exact)
    float s0 = expsum16(acc[0][0]) + expsum16(acc[0][1]);
    float s1 = expsum16(acc[1][0]) + expsum16(acc[1][1]);
    s0 += __shfl_xor(s0, 32);    // merge lane>>5 v-halves
    s1 += __shfl_xor(s1, 32);
    if (lane < 32) {
        ms[wn][2 * wm + 0][lane] = s0;
        ms[wn][2 * wm + 1][lane] = s1;
    }
    __syncthreads();

    // merge the 4 v-quarters (exp-space, linear -> exact), then lse + mean.
    // 128 block rows handled by 2 waves; one atomic per reducer wave.
    if (tid < 128) {
        const int g = tid >> 5, r = tid & 31;
        float e = (ms[0][g][r] + ms[1][g][r]) + (ms[2][g][r] + ms[3][g][r]);
        constexpr float TAU_LN2 = 1.3862943611198906f;  // tau*ln2 (v_log = log2)
        float lse = TAU_LN2 * __builtin_amdgcn_logf(e);
        #pragma unroll
        for (int m = 1; m < 64; m <<= 1) lse += __shfl_xor(lse, m);
        if ((tid & 63) == 0)
            atomicAdd(&out[bi * 32 + bj], lse * (1.0f / Na));  // 4rb x 2 = 8 adds
    }
}

extern "C" void kernel_launch(void* const* d_in, const int* in_sizes, int n_in,
                              void* d_out, int out_size, void* d_ws, size_t ws_size,
                              hipStream_t stream) {
    const float* audio  = (const float*)d_in[0];
    const float* visual = (const float*)d_in[1];
    float* out = (float*)d_out;

    unsigned char* a8 = (unsigned char*)d_ws;                        // 6.29 MB fp8 A
    unsigned char* b8 = a8 + (size_t)AGROUPS * GROUP_BYTES;          // +3.15 MB fp8 B

    convert_fp8_kernel<<<dim3(AGROUPS + BGROUPS), dim3(256), 0, stream>>>(
        audio, visual, a8, b8, out);
    // grid: 4096 blocks x 8 waves = 32768 waves
    //     = 32 bi x 32 bj x 4 row-blocks, block = 128 audio rows x 256 v
    gemm_lse_kernel<<<dim3(4096), dim3(512), 0, stream>>>(a8, b8, out);
}